// Round 10
// baseline (729.428 us; speedup 1.0000x reference)
//
#include <hip/hip_runtime.h>
#include <math.h>

#define E_EDGES 800000
#define N_ATOMS 50000
#define N_GRAPH 128
#define P_TBL   4096
#define SCAN_NB 49        // ceil(50000/1024)

static constexpr float PI_F   = 3.14159265358979323846f;
static constexpr float GSTEP  = 10.0f / 49.0f;                  // linspace(0,10,50) step
static constexpr float GCOEFF = -0.5f / (GSTEP * GSTEP);
static constexpr float DMAX   = 8.6603f;                        // > sqrt(75) = max possible d
static constexpr float DSCALE = (float)(P_TBL - 1) / DMAX;

// ---------------- counting sort by dst: histogram -> scan -> scatter ----------------
__global__ void hist_kernel(const int* __restrict__ dst, int* __restrict__ cnt) {
    int e = blockIdx.x * 256 + threadIdx.x;
    if (e < E_EDGES) atomicAdd(&cnt[dst[e]], 1);
}

__global__ __launch_bounds__(1024)
void scan1_kernel(const int* __restrict__ cnt, int* __restrict__ local_ex,
                  int* __restrict__ bsum) {
    __shared__ int sh[1024];
    const int t = threadIdx.x;
    const int i = blockIdx.x * 1024 + t;
    const int v = (i < N_ATOMS) ? cnt[i] : 0;
    sh[t] = v;
    __syncthreads();
    #pragma unroll
    for (int off = 1; off < 1024; off <<= 1) {
        int u = (t >= off) ? sh[t - off] : 0;
        __syncthreads();
        sh[t] += u;
        __syncthreads();
    }
    if (i < N_ATOMS) local_ex[i] = sh[t] - v;
    if (t == 1023) bsum[blockIdx.x] = sh[t];
}

__global__ __launch_bounds__(1024)
void scan2_kernel(const int* __restrict__ local_ex, const int* __restrict__ bsum,
                  int* __restrict__ starts, int* __restrict__ cursor) {
    __shared__ int off;
    const int b = blockIdx.x;
    if (threadIdx.x < 64) {
        int v = (threadIdx.x < b) ? bsum[threadIdx.x] : 0;   // SCAN_NB=49 < 64
        #pragma unroll
        for (int d = 32; d > 0; d >>= 1) v += __shfl_down(v, d, 64);
        if (threadIdx.x == 0) off = v;
    }
    __syncthreads();
    const int i = b * 1024 + threadIdx.x;
    if (i < N_ATOMS) {
        int v = local_ex[i] + off;
        starts[i] = v;
        cursor[i] = v;
    }
}

// scatter: inline distance; ONE packed 8B store per edge (src, d-bits)
__global__ void scatter_kernel(const int* __restrict__ ei, const float* __restrict__ pos,
                               int* __restrict__ cursor, uint2* __restrict__ pk) {
    int e = blockIdx.x * 256 + threadIdx.x;
    if (e >= E_EDGES) return;
    int sidx = ei[e];
    int dd   = ei[E_EDGES + e];
    float dx = pos[3*sidx+0] - pos[3*dd+0];
    float dy = pos[3*sidx+1] - pos[3*dd+1];
    float dz = pos[3*sidx+2] - pos[3*dd+2];
    float dist = sqrtf(dx*dx + dy*dy + dz*dz);
    int p = atomicAdd(&cursor[dd], 1);
    pk[p] = make_uint2((unsigned)sidx, __float_as_uint(dist));
}

// ---------------- filter-table build (float2-packed: row r holds (w[r], w[r+1])) ----------------
__global__ __launch_bounds__(256)
void table_kernel(const float* __restrict__ w1, const float* __restrict__ b1,
                  const float* __restrict__ w2, const float* __restrict__ b2,
                  float* __restrict__ tbl2) {   // float view of float2 array
    __shared__ float sa[4][52];
    __shared__ float st[4][64];
    const int l  = blockIdx.x >> 10;          // 1024 blocks per layer (4096/4 rows)
    const int rb = blockIdx.x & 1023;
    const int rr = threadIdx.x >> 6;          // row-in-block 0..3
    const int f  = threadIdx.x & 63;
    const int r  = rb * 4 + rr;
    const float dp = (float)r * (DMAX / (float)(P_TBL - 1));

    if (f < 50) {
        float t = dp - (float)f * GSTEP;
        sa[rr][f] = expf(GCOEFF * t * t);
    }
    __syncthreads();

    const float* W1 = w1 + (size_t)l * 50 * 64;
    const float* W2 = w2 + (size_t)l * 64 * 64;
    float t = b1[l * 64 + f];
    #pragma unroll 5
    for (int g = 0; g < 50; ++g) t = fmaf(sa[rr][g], W1[g * 64 + f], t);
    st[rr][f] = tanhf(t);
    __syncthreads();

    float w = b2[l * 64 + f];
    #pragma unroll 8
    for (int k = 0; k < 64; ++k) w = fmaf(st[rr][k], W2[k * 64 + f], w);
    float cutv = 0.5f * (cosf(dp * (PI_F / 10.0f)) + 1.0f);   // dp <= 8.66 < 10 always
    float val = w * cutv;
    const size_t base = ((size_t)l * P_TBL + r) * 64 + f;
    tbl2[base * 2 + 0] = val;                              // row r .x = w[r]
    if (r > 0) tbl2[(base - 64) * 2 + 1] = val;            // row r-1 .y = w[r]
}

// ---------------- embed + first lin GEMM fused (64-row tiles) ----------------
__global__ __launch_bounds__(256)
void embed_lin0_kernel(const int* __restrict__ z, const float* __restrict__ embed,
                       const float* __restrict__ W,
                       float* __restrict__ h, float* __restrict__ hj) {
    __shared__ float sA[64 * 65];
    __shared__ float sW[64 * 64];
    const int tid = threadIdx.x;
    const int rbase = blockIdx.x * 64;

    for (int i = tid; i < 64 * 64; i += 256) sW[i] = W[i];
    for (int i = tid; i < 64 * 64; i += 256) {
        int r = i >> 6, k = i & 63;
        int row = rbase + r;
        float v = 0.0f;
        if (row < N_ATOMS) {
            v = embed[(size_t)z[row] * 64 + k];
            h[(size_t)row * 64 + k] = v;
        }
        sA[r * 65 + k] = v;
    }
    __syncthreads();

    const int f0 = (tid & 7) * 8;
    const int r0 = (tid >> 3) * 2;
    float acc[2][8];
    #pragma unroll
    for (int i = 0; i < 2; ++i)
        #pragma unroll
        for (int j = 0; j < 8; ++j) acc[i][j] = 0.0f;

    #pragma unroll 4
    for (int k = 0; k < 64; ++k) {
        float a[2] = { sA[(r0+0)*65 + k], sA[(r0+1)*65 + k] };
        float4 wa = *(const float4*)&sW[k * 64 + f0];
        float4 wb = *(const float4*)&sW[k * 64 + f0 + 4];
        float w[8] = {wa.x, wa.y, wa.z, wa.w, wb.x, wb.y, wb.z, wb.w};
        #pragma unroll
        for (int i = 0; i < 2; ++i)
            #pragma unroll
            for (int j = 0; j < 8; ++j)
                acc[i][j] = fmaf(a[i], w[j], acc[i][j]);
    }

    #pragma unroll
    for (int i = 0; i < 2; ++i) {
        int row = rbase + r0 + i;
        if (row < N_ATOMS) {
            float* o = hj + (size_t)row * 64;
            *(float4*)&o[f0]     = make_float4(acc[i][0], acc[i][1], acc[i][2], acc[i][3]);
            *(float4*)&o[f0 + 4] = make_float4(acc[i][4], acc[i][5], acc[i][6], acc[i][7]);
        }
    }
}

// ---------------- packed-table lerp ----------------
__device__ __forceinline__ float edge_w2(const float2* __restrict__ tbl, float dist, int f) {
    float x = dist * DSCALE;
    int i0 = (int)x; i0 = (i0 > P_TBL - 2) ? (P_TBL - 2) : i0;
    float fr = x - (float)i0;
    float2 t = tbl[i0 * 64 + f];
    return fmaf(fr, t.y - t.x, t.x);
}

// ---------------- fused layer, 512 threads, wave-decoupled ----------------
// 64 nodes/block; wave wv owns rows [wv*8, wv*8+8): gathers them, then runs
// GEMM1 (h += agg@Wout + b) and GEMM2 (hj_out = h_new@Wlin) on ITS OWN rows.
// Only the cooperative weight staging needs a block barrier.
__global__ __launch_bounds__(512)
void layer_kernel(const uint2* __restrict__ pk,
                  const int* __restrict__ starts, const int* __restrict__ cnts,
                  const float* __restrict__ hj_in, const float2* __restrict__ tbl,
                  const float* __restrict__ Wout, const float* __restrict__ bout,
                  float* __restrict__ h,
                  const float* __restrict__ Wlin, float* __restrict__ hj_out,
                  int doLin) {
    __shared__ float sA[64 * 65];
    __shared__ float sW1[64 * 64];
    __shared__ float sW2[64 * 64];
    __shared__ float sb[64];
    const int tid = threadIdx.x;
    const int rbase = blockIdx.x * 64;
    const int f  = tid & 63;
    const int wv = tid >> 6;          // 0..7
    const int r0 = tid >> 3;          // 0..63  (GEMM row; wave wv owns rows 8wv..8wv+7)
    const int f0 = (tid & 7) * 8;
    const int myrow = rbase + r0;

    // early: preload this thread's h-row segment (block-exclusive rows)
    float4 hA = make_float4(0.f,0.f,0.f,0.f), hB = hA;
    if (myrow < N_ATOMS) {
        const float* hr = h + (size_t)myrow * 64;
        hA = *(const float4*)&hr[f0];
        hB = *(const float4*)&hr[f0 + 4];
    }

    // cooperative weight staging
    for (int i = tid; i < 64 * 64; i += 512) sW1[i] = Wout[i];
    if (doLin)
        for (int i = tid; i < 64 * 64; i += 512) sW2[i] = Wlin[i];
    if (tid < 64) sb[tid] = bout[tid];
    __syncthreads();          // the ONLY block barrier

    // ---- phase 1: gather-aggregate 8 nodes (wave-local rows) ----
    for (int i = 0; i < 8; ++i) {
        const int r = wv * 8 + i;
        const int n = rbase + r;
        float res = 0.0f;
        if (n < N_ATOMS) {
            const int s   = starts[n];
            const int end = s + cnts[n];
            float a0 = 0.0f, a1 = 0.0f, a2 = 0.0f, a3 = 0.0f;
            float a4 = 0.0f, a5 = 0.0f, a6 = 0.0f, a7 = 0.0f;
            int e = s;
            for (; e + 8 <= end; e += 8) {
                uint2 p0 = pk[e+0], p1 = pk[e+1], p2 = pk[e+2], p3 = pk[e+3];
                uint2 p4 = pk[e+4], p5 = pk[e+5], p6 = pk[e+6], p7 = pk[e+7];
                float w0 = edge_w2(tbl, __uint_as_float(p0.y), f);
                float w1 = edge_w2(tbl, __uint_as_float(p1.y), f);
                float w2 = edge_w2(tbl, __uint_as_float(p2.y), f);
                float w3 = edge_w2(tbl, __uint_as_float(p3.y), f);
                float w4 = edge_w2(tbl, __uint_as_float(p4.y), f);
                float w5 = edge_w2(tbl, __uint_as_float(p5.y), f);
                float w6 = edge_w2(tbl, __uint_as_float(p6.y), f);
                float w7 = edge_w2(tbl, __uint_as_float(p7.y), f);
                a0 = fmaf(w0, hj_in[(size_t)p0.x * 64 + f], a0);
                a1 = fmaf(w1, hj_in[(size_t)p1.x * 64 + f], a1);
                a2 = fmaf(w2, hj_in[(size_t)p2.x * 64 + f], a2);
                a3 = fmaf(w3, hj_in[(size_t)p3.x * 64 + f], a3);
                a4 = fmaf(w4, hj_in[(size_t)p4.x * 64 + f], a4);
                a5 = fmaf(w5, hj_in[(size_t)p5.x * 64 + f], a5);
                a6 = fmaf(w6, hj_in[(size_t)p6.x * 64 + f], a6);
                a7 = fmaf(w7, hj_in[(size_t)p7.x * 64 + f], a7);
            }
            for (; e + 2 <= end; e += 2) {
                uint2 p0 = pk[e], p1 = pk[e+1];
                float w0 = edge_w2(tbl, __uint_as_float(p0.y), f);
                float w1 = edge_w2(tbl, __uint_as_float(p1.y), f);
                a0 = fmaf(w0, hj_in[(size_t)p0.x * 64 + f], a0);
                a1 = fmaf(w1, hj_in[(size_t)p1.x * 64 + f], a1);
            }
            if (e < end) {
                uint2 p0 = pk[e];
                float w0 = edge_w2(tbl, __uint_as_float(p0.y), f);
                a0 = fmaf(w0, hj_in[(size_t)p0.x * 64 + f], a0);
            }
            res = ((a0 + a1) + (a2 + a3)) + ((a4 + a5) + (a6 + a7));
        }
        sA[r * 65 + f] = res;
    }
    __builtin_amdgcn_wave_barrier();   // compiler fence: gather writes before GEMM reads (same wave)

    // ---- phase 2: acc = h + sA@Wout + b  (reads only own row of sA) ----
    float acc[8];
    acc[0] = hA.x + sb[f0+0]; acc[1] = hA.y + sb[f0+1];
    acc[2] = hA.z + sb[f0+2]; acc[3] = hA.w + sb[f0+3];
    acc[4] = hB.x + sb[f0+4]; acc[5] = hB.y + sb[f0+5];
    acc[6] = hB.z + sb[f0+6]; acc[7] = hB.w + sb[f0+7];

    #pragma unroll 4
    for (int k = 0; k < 64; ++k) {
        float a = sA[r0 * 65 + k];
        float4 wa = *(const float4*)&sW1[k * 64 + f0];
        float4 wb = *(const float4*)&sW1[k * 64 + f0 + 4];
        acc[0] = fmaf(a, wa.x, acc[0]); acc[1] = fmaf(a, wa.y, acc[1]);
        acc[2] = fmaf(a, wa.z, acc[2]); acc[3] = fmaf(a, wa.w, acc[3]);
        acc[4] = fmaf(a, wb.x, acc[4]); acc[5] = fmaf(a, wb.y, acc[5]);
        acc[6] = fmaf(a, wb.z, acc[6]); acc[7] = fmaf(a, wb.w, acc[7]);
    }
    __builtin_amdgcn_wave_barrier();   // own-row reads done before overwrite (same wave)

    // ---- phase 3: write h_new, refill own row of sA ----
    if (myrow < N_ATOMS) {
        float* o = h + (size_t)myrow * 64;
        *(float4*)&o[f0]     = make_float4(acc[0], acc[1], acc[2], acc[3]);
        *(float4*)&o[f0 + 4] = make_float4(acc[4], acc[5], acc[6], acc[7]);
    }
    #pragma unroll
    for (int j = 0; j < 8; ++j) sA[r0 * 65 + f0 + j] = acc[j];
    if (!doLin) return;
    __builtin_amdgcn_wave_barrier();

    // ---- phase 4: hj_out = h_new @ Wlin (own row again) ----
    float acc2[8];
    #pragma unroll
    for (int j = 0; j < 8; ++j) acc2[j] = 0.0f;

    #pragma unroll 4
    for (int k = 0; k < 64; ++k) {
        float a = sA[r0 * 65 + k];
        float4 wa = *(const float4*)&sW2[k * 64 + f0];
        float4 wb = *(const float4*)&sW2[k * 64 + f0 + 4];
        acc2[0] = fmaf(a, wa.x, acc2[0]); acc2[1] = fmaf(a, wa.y, acc2[1]);
        acc2[2] = fmaf(a, wa.z, acc2[2]); acc2[3] = fmaf(a, wa.w, acc2[3]);
        acc2[4] = fmaf(a, wb.x, acc2[4]); acc2[5] = fmaf(a, wb.y, acc2[5]);
        acc2[6] = fmaf(a, wb.z, acc2[6]); acc2[7] = fmaf(a, wb.w, acc2[7]);
    }

    if (myrow < N_ATOMS) {
        float* o = hj_out + (size_t)myrow * 64;
        *(float4*)&o[f0]     = make_float4(acc2[0], acc2[1], acc2[2], acc2[3]);
        *(float4*)&o[f0 + 4] = make_float4(acc2[4], acc2[5], acc2[6], acc2[7]);
    }
}

// ---------------- fused pool + head ----------------
__global__ __launch_bounds__(256)
void pool_head_kernel(const float* __restrict__ h, const int* __restrict__ batch,
                      const float* __restrict__ fc1w, const float* __restrict__ fc1b,
                      const float* __restrict__ fc2w, const float* __restrict__ fc2b,
                      float* __restrict__ out) {
    __shared__ float part[4][64];
    __shared__ float sp[64];
    __shared__ float sx[32];
    __shared__ int bounds[2];
    const int g   = blockIdx.x;
    const int tid = threadIdx.x;

    if (tid < 2) {
        int target = g + tid;
        int lo = 0, hi = N_ATOMS;
        while (lo < hi) {
            int m = (lo + hi) >> 1;
            if (batch[m] < target) lo = m + 1; else hi = m;
        }
        bounds[tid] = lo;
    }
    __syncthreads();
    const int s = bounds[0], epos = bounds[1];

    const int f = tid & 63, wv = tid >> 6;
    float a = 0.0f;
    for (int r = s + wv; r < epos; r += 4) a += h[(size_t)r * 64 + f];
    part[wv][f] = a;
    __syncthreads();

    if (tid < 64) {
        float cnt = (float)(epos - s);
        sp[tid] = (part[0][tid] + part[1][tid] + part[2][tid] + part[3][tid])
                  / fmaxf(cnt, 1.0f);
    }
    __syncthreads();
    if (tid < 32) {
        float a1 = fc1b[tid];
        #pragma unroll 8
        for (int k = 0; k < 64; ++k) a1 = fmaf(sp[k], fc1w[k * 32 + tid], a1);
        sx[tid] = fmaxf(a1, 0.0f);
    }
    __syncthreads();
    if (tid == 0) {
        float a2 = fc2b[0];
        #pragma unroll 8
        for (int j = 0; j < 32; ++j) a2 = fmaf(sx[j], fc2w[j], a2);
        out[g] = a2;
    }
}

extern "C" void kernel_launch(void* const* d_in, const int* in_sizes, int n_in,
                              void* d_out, int out_size, void* d_ws, size_t ws_size,
                              hipStream_t stream) {
    const int*   z         = (const int*)  d_in[0];
    const float* pos       = (const float*)d_in[1];
    const int*   batch     = (const int*)  d_in[2];
    const int*   ei        = (const int*)  d_in[3];
    const float* embed     = (const float*)d_in[4];
    const float* mlp_w1    = (const float*)d_in[5];
    const float* mlp_b1    = (const float*)d_in[6];
    const float* mlp_w2    = (const float*)d_in[7];
    const float* mlp_b2    = (const float*)d_in[8];
    const float* lin_w     = (const float*)d_in[9];
    const float* lin_out_w = (const float*)d_in[10];
    const float* lin_out_b = (const float*)d_in[11];
    const float* fc1w      = (const float*)d_in[12];
    const float* fc1b      = (const float*)d_in[13];
    const float* fc2w      = (const float*)d_in[14];
    const float* fc2b      = (const float*)d_in[15];
    float* out = (float*)d_out;

    float*  ws    = (float*)d_ws;
    float*  h     = ws;                            // [N,64]
    float*  hj0   = h     + (size_t)N_ATOMS * 64;  // [N,64] ping
    float*  hj1   = hj0   + (size_t)N_ATOMS * 64;  // [N,64] pong
    float2* tbl   = (float2*)(hj1 + (size_t)N_ATOMS * 64);  // [6,P_TBL,64] float2
    uint2*  pk    = (uint2*)(tbl + (size_t)6 * P_TBL * 64); // [E] packed (src, d)
    int*    hist  = (int*)(pk + E_EDGES);          // [N]
    int*    starts= hist  + N_ATOMS;               // [N]
    int*    cursor= starts+ N_ATOMS;               // [N]
    int*    lex   = cursor+ N_ATOMS;               // [N] scan temp
    int*    bsum  = lex   + N_ATOMS;               // [SCAN_NB]

    const int* dst = ei + E_EDGES;

    // ---- once per launch: counting sort by dst (distance inline) + table build ----
    hipMemsetAsync(hist, 0, N_ATOMS * sizeof(int), stream);
    hist_kernel<<<E_EDGES / 256, 256, 0, stream>>>(dst, hist);
    scan1_kernel<<<SCAN_NB, 1024, 0, stream>>>(hist, lex, bsum);
    scan2_kernel<<<SCAN_NB, 1024, 0, stream>>>(lex, bsum, starts, cursor);
    scatter_kernel<<<E_EDGES / 256, 256, 0, stream>>>(ei, pos, cursor, pk);
    table_kernel<<<6 * (P_TBL / 4), 256, 0, stream>>>(mlp_w1, mlp_b1, mlp_w2, mlp_b2,
                                                      (float*)tbl);

    const int ngemm_grid = (N_ATOMS + 63) / 64;

    embed_lin0_kernel<<<ngemm_grid, 256, 0, stream>>>(z, embed, lin_w, h, hj0);

    float* hjbuf[2] = { hj0, hj1 };
    for (int l = 0; l < 6; ++l) {
        layer_kernel<<<ngemm_grid, 512, 0, stream>>>(
            pk, starts, hist, hjbuf[l & 1], tbl + (size_t)l * P_TBL * 64,
            lin_out_w + (size_t)l * 64 * 64, lin_out_b + (size_t)l * 64, h,
            (l < 5) ? (lin_w + (size_t)(l + 1) * 64 * 64) : nullptr,
            hjbuf[(l + 1) & 1], (l < 5) ? 1 : 0);
    }

    pool_head_kernel<<<N_GRAPH, 256, 0, stream>>>(h, batch, fc1w, fc1b, fc2w, fc2b, out);
}

// Round 11
// 707.711 us; speedup vs baseline: 1.0307x; 1.0307x over previous
//
#include <hip/hip_runtime.h>
#include <hip/hip_fp16.h>
#include <math.h>

#define E_EDGES 800000
#define N_ATOMS 50000
#define N_GRAPH 128
#define P_TBL   2048
#define SCAN_NB 49        // ceil(50000/1024)

static constexpr float PI_F   = 3.14159265358979323846f;
static constexpr float GSTEP  = 10.0f / 49.0f;                  // linspace(0,10,50) step
static constexpr float GCOEFF = -0.5f / (GSTEP * GSTEP);
static constexpr float DMAX   = 8.6603f;                        // > sqrt(75) = max possible d
static constexpr float DSCALE = (float)(P_TBL - 1) / DMAX;

// ---------------- counting sort by dst: histogram -> scan -> scatter ----------------
__global__ void hist_kernel(const int* __restrict__ dst, int* __restrict__ cnt) {
    int e = blockIdx.x * 256 + threadIdx.x;
    if (e < E_EDGES) atomicAdd(&cnt[dst[e]], 1);
}

__global__ __launch_bounds__(1024)
void scan1_kernel(const int* __restrict__ cnt, int* __restrict__ local_ex,
                  int* __restrict__ bsum) {
    __shared__ int sh[1024];
    const int t = threadIdx.x;
    const int i = blockIdx.x * 1024 + t;
    const int v = (i < N_ATOMS) ? cnt[i] : 0;
    sh[t] = v;
    __syncthreads();
    #pragma unroll
    for (int off = 1; off < 1024; off <<= 1) {
        int u = (t >= off) ? sh[t - off] : 0;
        __syncthreads();
        sh[t] += u;
        __syncthreads();
    }
    if (i < N_ATOMS) local_ex[i] = sh[t] - v;
    if (t == 1023) bsum[blockIdx.x] = sh[t];
}

__global__ __launch_bounds__(1024)
void scan2_kernel(const int* __restrict__ local_ex, const int* __restrict__ bsum,
                  int* __restrict__ starts, int* __restrict__ cursor) {
    __shared__ int off;
    const int b = blockIdx.x;
    if (threadIdx.x < 64) {
        int v = (threadIdx.x < b) ? bsum[threadIdx.x] : 0;   // SCAN_NB=49 < 64
        #pragma unroll
        for (int d = 32; d > 0; d >>= 1) v += __shfl_down(v, d, 64);
        if (threadIdx.x == 0) off = v;
    }
    __syncthreads();
    const int i = b * 1024 + threadIdx.x;
    if (i < N_ATOMS) {
        int v = local_ex[i] + off;
        starts[i] = v;
        cursor[i] = v;
    }
}

// scatter: inline distance; ONE packed 8B store per edge (src, d-bits)
__global__ void scatter_kernel(const int* __restrict__ ei, const float* __restrict__ pos,
                               int* __restrict__ cursor, uint2* __restrict__ pk) {
    int e = blockIdx.x * 256 + threadIdx.x;
    if (e >= E_EDGES) return;
    int sidx = ei[e];
    int dd   = ei[E_EDGES + e];
    float dx = pos[3*sidx+0] - pos[3*dd+0];
    float dy = pos[3*sidx+1] - pos[3*dd+1];
    float dz = pos[3*sidx+2] - pos[3*dd+2];
    float dist = sqrtf(dx*dx + dy*dy + dz*dz);
    int p = atomicAdd(&cursor[dd], 1);
    pk[p] = make_uint2((unsigned)sidx, __float_as_uint(dist));
}

// ---------------- filter-table build (float2-packed: row r holds (w[r], w[r+1])) ----------------
__global__ __launch_bounds__(256)
void table_kernel(const float* __restrict__ w1, const float* __restrict__ b1,
                  const float* __restrict__ w2, const float* __restrict__ b2,
                  float* __restrict__ tbl2) {   // float view of float2 array
    __shared__ float sa[4][52];
    __shared__ float st[4][64];
    const int l  = blockIdx.x >> 9;           // 512 blocks per layer (2048/4 rows)
    const int rb = blockIdx.x & 511;
    const int rr = threadIdx.x >> 6;          // row-in-block 0..3
    const int f  = threadIdx.x & 63;
    const int r  = rb * 4 + rr;
    const float dp = (float)r * (DMAX / (float)(P_TBL - 1));

    if (f < 50) {
        float t = dp - (float)f * GSTEP;
        sa[rr][f] = expf(GCOEFF * t * t);
    }
    __syncthreads();

    const float* W1 = w1 + (size_t)l * 50 * 64;
    const float* W2 = w2 + (size_t)l * 64 * 64;
    float t = b1[l * 64 + f];
    #pragma unroll 5
    for (int g = 0; g < 50; ++g) t = fmaf(sa[rr][g], W1[g * 64 + f], t);
    st[rr][f] = tanhf(t);
    __syncthreads();

    float w = b2[l * 64 + f];
    #pragma unroll 8
    for (int k = 0; k < 64; ++k) w = fmaf(st[rr][k], W2[k * 64 + f], w);
    float cutv = 0.5f * (cosf(dp * (PI_F / 10.0f)) + 1.0f);   // dp <= 8.66 < 10 always
    float val = w * cutv;
    const size_t base = ((size_t)l * P_TBL + r) * 64 + f;
    tbl2[base * 2 + 0] = val;                              // row r .x = w[r]
    if (r > 0) tbl2[(base - 64) * 2 + 1] = val;            // row r-1 .y = w[r]
}

// ---------------- fp16 pack helper ----------------
__device__ __forceinline__ void store_half8(__half* dst, const float* v) {
    union { ushort u[8]; uint4 q; } p;
    #pragma unroll
    for (int j = 0; j < 8; ++j) p.u[j] = __half_as_ushort(__float2half(v[j]));
    *(uint4*)dst = p.q;
}

// ---------------- embed + first lin GEMM fused (64-row tiles; hj out in fp16) ----------------
__global__ __launch_bounds__(256)
void embed_lin0_kernel(const int* __restrict__ z, const float* __restrict__ embed,
                       const float* __restrict__ W,
                       float* __restrict__ h, __half* __restrict__ hj) {
    __shared__ float sA[64 * 65];
    __shared__ float sW[64 * 64];
    const int tid = threadIdx.x;
    const int rbase = blockIdx.x * 64;

    for (int i = tid; i < 64 * 64; i += 256) sW[i] = W[i];
    for (int i = tid; i < 64 * 64; i += 256) {
        int r = i >> 6, k = i & 63;
        int row = rbase + r;
        float v = 0.0f;
        if (row < N_ATOMS) {
            v = embed[(size_t)z[row] * 64 + k];
            h[(size_t)row * 64 + k] = v;
        }
        sA[r * 65 + k] = v;
    }
    __syncthreads();

    const int f0 = (tid & 7) * 8;
    const int r0 = (tid >> 3) * 2;
    float acc[2][8];
    #pragma unroll
    for (int i = 0; i < 2; ++i)
        #pragma unroll
        for (int j = 0; j < 8; ++j) acc[i][j] = 0.0f;

    #pragma unroll 4
    for (int k = 0; k < 64; ++k) {
        float a[2] = { sA[(r0+0)*65 + k], sA[(r0+1)*65 + k] };
        float4 wa = *(const float4*)&sW[k * 64 + f0];
        float4 wb = *(const float4*)&sW[k * 64 + f0 + 4];
        float w[8] = {wa.x, wa.y, wa.z, wa.w, wb.x, wb.y, wb.z, wb.w};
        #pragma unroll
        for (int i = 0; i < 2; ++i)
            #pragma unroll
            for (int j = 0; j < 8; ++j)
                acc[i][j] = fmaf(a[i], w[j], acc[i][j]);
    }

    #pragma unroll
    for (int i = 0; i < 2; ++i) {
        int row = rbase + r0 + i;
        if (row < N_ATOMS)
            store_half8(hj + (size_t)row * 64 + f0, acc[i]);
    }
}

// ---------------- packed-table lerp ----------------
__device__ __forceinline__ float edge_w2(const float2* __restrict__ tbl, float dist, int f) {
    float x = dist * DSCALE;
    int i0 = (int)x; i0 = (i0 > P_TBL - 2) ? (P_TBL - 2) : i0;
    float fr = x - (float)i0;
    float2 t = tbl[i0 * 64 + f];
    return fmaf(fr, t.y - t.x, t.x);
}

// ---------------- fused layer, 512 threads, wave-decoupled, fp16 hj ----------------
__global__ __launch_bounds__(512)
void layer_kernel(const uint2* __restrict__ pk,
                  const int* __restrict__ starts, const int* __restrict__ cnts,
                  const __half* __restrict__ hj_in, const float2* __restrict__ tbl,
                  const float* __restrict__ Wout, const float* __restrict__ bout,
                  float* __restrict__ h,
                  const float* __restrict__ Wlin, __half* __restrict__ hj_out,
                  int doLin) {
    __shared__ float sA[64 * 65];
    __shared__ float sW1[64 * 64];
    __shared__ float sW2[64 * 64];
    __shared__ float sb[64];
    const int tid = threadIdx.x;
    const int rbase = blockIdx.x * 64;
    const int f  = tid & 63;
    const int wv = tid >> 6;          // 0..7
    const int r0 = tid >> 3;          // 0..63  (GEMM row; wave wv owns rows 8wv..8wv+7)
    const int f0 = (tid & 7) * 8;
    const int myrow = rbase + r0;

    // early: preload this thread's h-row segment (block-exclusive rows)
    float4 hA = make_float4(0.f,0.f,0.f,0.f), hB = hA;
    if (myrow < N_ATOMS) {
        const float* hr = h + (size_t)myrow * 64;
        hA = *(const float4*)&hr[f0];
        hB = *(const float4*)&hr[f0 + 4];
    }

    // cooperative weight staging
    for (int i = tid; i < 64 * 64; i += 512) sW1[i] = Wout[i];
    if (doLin)
        for (int i = tid; i < 64 * 64; i += 512) sW2[i] = Wlin[i];
    if (tid < 64) sb[tid] = bout[tid];
    __syncthreads();          // the ONLY block barrier

    // ---- phase 1: gather-aggregate 8 nodes (wave-local rows) ----
    for (int i = 0; i < 8; ++i) {
        const int r = wv * 8 + i;
        const int n = rbase + r;
        float res = 0.0f;
        if (n < N_ATOMS) {
            const int s   = starts[n];
            const int end = s + cnts[n];
            float a0 = 0.0f, a1 = 0.0f, a2 = 0.0f, a3 = 0.0f;
            float a4 = 0.0f, a5 = 0.0f, a6 = 0.0f, a7 = 0.0f;
            int e = s;
            for (; e + 8 <= end; e += 8) {
                uint2 p0 = pk[e+0], p1 = pk[e+1], p2 = pk[e+2], p3 = pk[e+3];
                uint2 p4 = pk[e+4], p5 = pk[e+5], p6 = pk[e+6], p7 = pk[e+7];
                float w0 = edge_w2(tbl, __uint_as_float(p0.y), f);
                float w1 = edge_w2(tbl, __uint_as_float(p1.y), f);
                float w2 = edge_w2(tbl, __uint_as_float(p2.y), f);
                float w3 = edge_w2(tbl, __uint_as_float(p3.y), f);
                float w4 = edge_w2(tbl, __uint_as_float(p4.y), f);
                float w5 = edge_w2(tbl, __uint_as_float(p5.y), f);
                float w6 = edge_w2(tbl, __uint_as_float(p6.y), f);
                float w7 = edge_w2(tbl, __uint_as_float(p7.y), f);
                a0 = fmaf(w0, __half2float(hj_in[(size_t)p0.x * 64 + f]), a0);
                a1 = fmaf(w1, __half2float(hj_in[(size_t)p1.x * 64 + f]), a1);
                a2 = fmaf(w2, __half2float(hj_in[(size_t)p2.x * 64 + f]), a2);
                a3 = fmaf(w3, __half2float(hj_in[(size_t)p3.x * 64 + f]), a3);
                a4 = fmaf(w4, __half2float(hj_in[(size_t)p4.x * 64 + f]), a4);
                a5 = fmaf(w5, __half2float(hj_in[(size_t)p5.x * 64 + f]), a5);
                a6 = fmaf(w6, __half2float(hj_in[(size_t)p6.x * 64 + f]), a6);
                a7 = fmaf(w7, __half2float(hj_in[(size_t)p7.x * 64 + f]), a7);
            }
            for (; e + 2 <= end; e += 2) {
                uint2 p0 = pk[e], p1 = pk[e+1];
                float w0 = edge_w2(tbl, __uint_as_float(p0.y), f);
                float w1 = edge_w2(tbl, __uint_as_float(p1.y), f);
                a0 = fmaf(w0, __half2float(hj_in[(size_t)p0.x * 64 + f]), a0);
                a1 = fmaf(w1, __half2float(hj_in[(size_t)p1.x * 64 + f]), a1);
            }
            if (e < end) {
                uint2 p0 = pk[e];
                float w0 = edge_w2(tbl, __uint_as_float(p0.y), f);
                a0 = fmaf(w0, __half2float(hj_in[(size_t)p0.x * 64 + f]), a0);
            }
            res = ((a0 + a1) + (a2 + a3)) + ((a4 + a5) + (a6 + a7));
        }
        sA[r * 65 + f] = res;
    }
    __builtin_amdgcn_wave_barrier();   // fence: gather writes before GEMM reads (same wave)

    // ---- phase 2: acc = h + sA@Wout + b  (reads only own row of sA) ----
    float acc[8];
    acc[0] = hA.x + sb[f0+0]; acc[1] = hA.y + sb[f0+1];
    acc[2] = hA.z + sb[f0+2]; acc[3] = hA.w + sb[f0+3];
    acc[4] = hB.x + sb[f0+4]; acc[5] = hB.y + sb[f0+5];
    acc[6] = hB.z + sb[f0+6]; acc[7] = hB.w + sb[f0+7];

    #pragma unroll 4
    for (int k = 0; k < 64; ++k) {
        float a = sA[r0 * 65 + k];
        float4 wa = *(const float4*)&sW1[k * 64 + f0];
        float4 wb = *(const float4*)&sW1[k * 64 + f0 + 4];
        acc[0] = fmaf(a, wa.x, acc[0]); acc[1] = fmaf(a, wa.y, acc[1]);
        acc[2] = fmaf(a, wa.z, acc[2]); acc[3] = fmaf(a, wa.w, acc[3]);
        acc[4] = fmaf(a, wb.x, acc[4]); acc[5] = fmaf(a, wb.y, acc[5]);
        acc[6] = fmaf(a, wb.z, acc[6]); acc[7] = fmaf(a, wb.w, acc[7]);
    }
    __builtin_amdgcn_wave_barrier();   // own-row reads done before overwrite (same wave)

    // ---- phase 3: write h_new, refill own row of sA ----
    if (myrow < N_ATOMS) {
        float* o = h + (size_t)myrow * 64;
        *(float4*)&o[f0]     = make_float4(acc[0], acc[1], acc[2], acc[3]);
        *(float4*)&o[f0 + 4] = make_float4(acc[4], acc[5], acc[6], acc[7]);
    }
    #pragma unroll
    for (int j = 0; j < 8; ++j) sA[r0 * 65 + f0 + j] = acc[j];
    if (!doLin) return;
    __builtin_amdgcn_wave_barrier();

    // ---- phase 4: hj_out = h_new @ Wlin (own row again), fp16 store ----
    float acc2[8];
    #pragma unroll
    for (int j = 0; j < 8; ++j) acc2[j] = 0.0f;

    #pragma unroll 4
    for (int k = 0; k < 64; ++k) {
        float a = sA[r0 * 65 + k];
        float4 wa = *(const float4*)&sW2[k * 64 + f0];
        float4 wb = *(const float4*)&sW2[k * 64 + f0 + 4];
        acc2[0] = fmaf(a, wa.x, acc2[0]); acc2[1] = fmaf(a, wa.y, acc2[1]);
        acc2[2] = fmaf(a, wa.z, acc2[2]); acc2[3] = fmaf(a, wa.w, acc2[3]);
        acc2[4] = fmaf(a, wb.x, acc2[4]); acc2[5] = fmaf(a, wb.y, acc2[5]);
        acc2[6] = fmaf(a, wb.z, acc2[6]); acc2[7] = fmaf(a, wb.w, acc2[7]);
    }

    if (myrow < N_ATOMS)
        store_half8(hj_out + (size_t)myrow * 64 + f0, acc2);
}

// ---------------- fused pool + head ----------------
__global__ __launch_bounds__(256)
void pool_head_kernel(const float* __restrict__ h, const int* __restrict__ batch,
                      const float* __restrict__ fc1w, const float* __restrict__ fc1b,
                      const float* __restrict__ fc2w, const float* __restrict__ fc2b,
                      float* __restrict__ out) {
    __shared__ float part[4][64];
    __shared__ float sp[64];
    __shared__ float sx[32];
    __shared__ int bounds[2];
    const int g   = blockIdx.x;
    const int tid = threadIdx.x;

    if (tid < 2) {
        int target = g + tid;
        int lo = 0, hi = N_ATOMS;
        while (lo < hi) {
            int m = (lo + hi) >> 1;
            if (batch[m] < target) lo = m + 1; else hi = m;
        }
        bounds[tid] = lo;
    }
    __syncthreads();
    const int s = bounds[0], epos = bounds[1];

    const int f = tid & 63, wv = tid >> 6;
    float a = 0.0f;
    for (int r = s + wv; r < epos; r += 4) a += h[(size_t)r * 64 + f];
    part[wv][f] = a;
    __syncthreads();

    if (tid < 64) {
        float cnt = (float)(epos - s);
        sp[tid] = (part[0][tid] + part[1][tid] + part[2][tid] + part[3][tid])
                  / fmaxf(cnt, 1.0f);
    }
    __syncthreads();
    if (tid < 32) {
        float a1 = fc1b[tid];
        #pragma unroll 8
        for (int k = 0; k < 64; ++k) a1 = fmaf(sp[k], fc1w[k * 32 + tid], a1);
        sx[tid] = fmaxf(a1, 0.0f);
    }
    __syncthreads();
    if (tid == 0) {
        float a2 = fc2b[0];
        #pragma unroll 8
        for (int j = 0; j < 32; ++j) a2 = fmaf(sx[j], fc2w[j], a2);
        out[g] = a2;
    }
}

extern "C" void kernel_launch(void* const* d_in, const int* in_sizes, int n_in,
                              void* d_out, int out_size, void* d_ws, size_t ws_size,
                              hipStream_t stream) {
    const int*   z         = (const int*)  d_in[0];
    const float* pos       = (const float*)d_in[1];
    const int*   batch     = (const int*)  d_in[2];
    const int*   ei        = (const int*)  d_in[3];
    const float* embed     = (const float*)d_in[4];
    const float* mlp_w1    = (const float*)d_in[5];
    const float* mlp_b1    = (const float*)d_in[6];
    const float* mlp_w2    = (const float*)d_in[7];
    const float* mlp_b2    = (const float*)d_in[8];
    const float* lin_w     = (const float*)d_in[9];
    const float* lin_out_w = (const float*)d_in[10];
    const float* lin_out_b = (const float*)d_in[11];
    const float* fc1w      = (const float*)d_in[12];
    const float* fc1b      = (const float*)d_in[13];
    const float* fc2w      = (const float*)d_in[14];
    const float* fc2b      = (const float*)d_in[15];
    float* out = (float*)d_out;

    char* base = (char*)d_ws;
    const size_t HB = (size_t)N_ATOMS * 64 * sizeof(float);     // 12.8 MB
    const size_t HJ = (size_t)N_ATOMS * 64 * sizeof(__half);    // 6.4 MB
    float*  h     = (float*)base;
    __half* hj0   = (__half*)(base + HB);
    __half* hj1   = (__half*)(base + HB + HJ);
    float2* tbl   = (float2*)(base + HB + 2 * HJ);
    uint2*  pk    = (uint2*)(tbl + (size_t)6 * P_TBL * 64);
    int*    hist  = (int*)(pk + E_EDGES);
    int*    starts= hist  + N_ATOMS;
    int*    cursor= starts+ N_ATOMS;
    int*    lex   = cursor+ N_ATOMS;
    int*    bsum  = lex   + N_ATOMS;

    const int* dst = ei + E_EDGES;

    // ---- once per launch: counting sort by dst (distance inline) + table build ----
    hipMemsetAsync(hist, 0, N_ATOMS * sizeof(int), stream);
    hist_kernel<<<E_EDGES / 256, 256, 0, stream>>>(dst, hist);
    scan1_kernel<<<SCAN_NB, 1024, 0, stream>>>(hist, lex, bsum);
    scan2_kernel<<<SCAN_NB, 1024, 0, stream>>>(lex, bsum, starts, cursor);
    scatter_kernel<<<E_EDGES / 256, 256, 0, stream>>>(ei, pos, cursor, pk);
    table_kernel<<<6 * (P_TBL / 4), 256, 0, stream>>>(mlp_w1, mlp_b1, mlp_w2, mlp_b2,
                                                      (float*)tbl);

    const int ngemm_grid = (N_ATOMS + 63) / 64;

    embed_lin0_kernel<<<ngemm_grid, 256, 0, stream>>>(z, embed, lin_w, h, hj0);

    __half* hjbuf[2] = { hj0, hj1 };
    for (int l = 0; l < 6; ++l) {
        layer_kernel<<<ngemm_grid, 512, 0, stream>>>(
            pk, starts, hist, hjbuf[l & 1], tbl + (size_t)l * P_TBL * 64,
            lin_out_w + (size_t)l * 64 * 64, lin_out_b + (size_t)l * 64, h,
            (l < 5) ? (lin_w + (size_t)(l + 1) * 64 * 64) : nullptr,
            hjbuf[(l + 1) & 1], (l < 5) ? 1 : 0);
    }

    pool_head_kernel<<<N_GRAPH, 256, 0, stream>>>(h, batch, fc1w, fc1b, fc2w, fc2b, out);
}